// Round 11
// baseline (186.776 us; speedup 1.0000x reference)
//
#include <hip/hip_runtime.h>

// Batched 2D db4 DWT (pywt dwt2, mode='symmetric') over [8,32,512,512] f32.
// Output [4, 8, 32, 259, 259] f32 (LL, LH, HL, HH).
//
//   y[o] = sum_k ext[2o+1+k] * G[k],  G[k] = F[7-k]
//   ext index j -> src:  j<7 -> 6-j ; j<=518 -> j-7 ; else 1030-j
//
// v11 = v7 structure (streaming walker, depth-1 prefetch, interior/edge
// split, plain f4 stores) but ROLLED: prologue (rows 0-5, static) + a
// 3-iteration loop over an 8-row steady-state body. The slot schedule is
// periodic mod 8 rows, so all P[][] indices stay compile-time constants.
// Rationale: v4-v10 unrolled 30 rows (~35 KB code) > 32 KB I$ -> waves at
// different phases thrash instruction fetch (explains low VALUBusy + low BW
// + multi-thousand-cycle stalls insensitive to wave count). Body now ~15 KB
// and all 4 waves/block share the same loop.

namespace {

constexpr int N    = 512;
constexpr int HO   = 259;
constexpr int NBC  = 256;
constexpr int TOH  = 12;                     // output rows per strip
constexpr int NS   = 22;                     // strips (22*12 = 264 >= 259)
constexpr int MIDR = 2 * TOH + 6;            // 30 mid rows per strip

constexpr int NCGI   = 63;                   // interior 4-col groups (cg = 1..63)
constexpr int IITEMS = NBC * NS * NCGI;      // 354,816
constexpr int IBLK   = IITEMS / 256;         // 1386 (exact)
constexpr int EITEMS = NBC * NS * 2;         // 11,264
constexpr int EBLK   = EITEMS / 256;         // 44 (exact)
constexpr int EHALF  = EITEMS / 2;           // 5632 (= 88 waves)

typedef float f4 __attribute__((ext_vector_type(4)));
typedef f4 __attribute__((aligned(4))) f4u;

__device__ constexpr float GL[8] = {
     0.23037781330885523f,  0.7148465705525415f,   0.6308807679295904f,
    -0.02798376941698385f, -0.18703481171888114f,  0.030841381835986965f,
     0.032883011666982945f,-0.010597401784997278f};
__device__ constexpr float GH[8] = {
    -0.010597401784997278f,-0.032883011666982945f, 0.030841381835986965f,
     0.18703481171888114f, -0.02798376941698385f, -0.6308807679295904f,
     0.7148465705525415f,  -0.23037781330885523f};

// Tap f -> index into the 16-float window loaded from base ab.
// interior (ab = 8cg-8): tap f = win[2+f]
// cg==0   (ab = 0)     : ext[1+f]   -> LMAP
// cg==64  (ab = 496)   : ext[513+f] -> RMAP
__device__ constexpr int LMAP[14] = {5,4,3,2,1,0,0,1,2,3,4,5,6,7};
__device__ constexpr int RMAP[14] = {10,11,12,13,14,15,15,14,13,12,11,10,9,8};

__device__ __forceinline__ int ext_row(int j) {
    int v = j - 7;
    v = (j < 7)     ? (6 - j)         : v;
    v = (j > N + 6) ? (2 * N + 6 - j) : v;
    return v;
}

template <int MODE>
__device__ __forceinline__ void hconv16(const f4& A, const f4& B, const f4& C,
                                        const f4& D, f4& lo, f4& hi) {
    const float win[16] = {A.x,A.y,A.z,A.w, B.x,B.y,B.z,B.w,
                           C.x,C.y,C.z,C.w, D.x,D.y,D.z,D.w};
    float v[14];
    if constexpr (MODE == 0) {
        #pragma unroll
        for (int f = 0; f < 14; ++f) v[f] = win[2 + f];
    } else if constexpr (MODE < 0) {
        #pragma unroll
        for (int f = 0; f < 14; ++f) v[f] = win[LMAP[f]];
    } else {
        #pragma unroll
        for (int f = 0; f < 14; ++f) v[f] = win[RMAP[f]];
    }
    #pragma unroll
    for (int o = 0; o < 4; ++o) {
        float l = 0.f, h = 0.f;
        #pragma unroll
        for (int k = 0; k < 8; ++k) {
            l = fmaf(v[2 * o + k], GL[k], l);
            h = fmaf(v[2 * o + k], GH[k], h);
        }
        lo[o] = l; hi[o] = h;
    }
}

template <int MODE>
__device__ __forceinline__ void strip_body(const float* __restrict__ img,
                                           float* __restrict__ obase,
                                           size_t sub, int eh0, int st,
                                           int c0, int ab) {
    // pending accumulators: P[slot][0..3] = ll, lh, hl, hh (all indices static)
    f4 P[4][4];
    #pragma unroll
    for (int s = 0; s < 4; ++s)
        #pragma unroll
        for (int q = 0; q < 4; ++q) P[s][q] = (f4){0.f, 0.f, 0.f, 0.f};

    f4 b0a, b0b, b0c, b0d, b1a, b1b, b1c, b1d;

#define PRE(rn_, A_, B_, C_, D_) do {                                         \
    const float* rp_ = img + (size_t)ext_row(eh0 + (rn_)) * N + ab;           \
    A_ = *(const f4*)(rp_);      B_ = *(const f4*)(rp_ + 4);                  \
    C_ = *(const f4*)(rp_ + 8);  D_ = *(const f4*)(rp_ + 12);                 \
} while (0)

#define UPDK(k_, s_) do {                                                     \
    const float gl_ = GL[k_], gh_ = GH[k_];                                   \
    P[s_][0] += lo * gl_;  P[s_][1] += lo * gh_;                              \
    P[s_][2] += hi * gl_;  P[s_][3] += hi * gh_;                              \
} while (0)

#define FINS(s_, uo_) do {                                                    \
    const int ho_ = st * TOH + (uo_);                                         \
    if (ho_ < HO) {                                                           \
        const size_t p_ = (size_t)ho_ * HO + c0;                              \
        if constexpr (MODE != 1) {                                            \
            *(f4u*)(obase + p_)           = P[s_][0];                         \
            *(f4u*)(obase + sub + p_)     = P[s_][1];                         \
            *(f4u*)(obase + 2 * sub + p_) = P[s_][2];                         \
            *(f4u*)(obase + 3 * sub + p_) = P[s_][3];                         \
        } else {                                                              \
            _Pragma("unroll")                                                 \
            for (int o = 0; o < 3; ++o) {                                     \
                obase[p_ + o]           = P[s_][0][o];                        \
                obase[sub + p_ + o]     = P[s_][1][o];                        \
                obase[2 * sub + p_ + o] = P[s_][2][o];                        \
                obase[3 * sub + p_ + o] = P[s_][3][o];                        \
            }                                                                 \
        }                                                                     \
    }                                                                         \
    P[s_][0] = (f4){0.f,0.f,0.f,0.f};  P[s_][1] = (f4){0.f,0.f,0.f,0.f};     \
    P[s_][2] = (f4){0.f,0.f,0.f,0.f};  P[s_][3] = (f4){0.f,0.f,0.f,0.f};     \
} while (0)
// NOTE: FINS resets all 4? No — reset only s_:
#undef FINS
#define FINS(s_, uo_) do {                                                    \
    const int ho_ = st * TOH + (uo_);                                         \
    if (ho_ < HO) {                                                           \
        const size_t p_ = (size_t)ho_ * HO + c0;                              \
        if constexpr (MODE != 1) {                                            \
            *(f4u*)(obase + p_)           = P[s_][0];                         \
            *(f4u*)(obase + sub + p_)     = P[s_][1];                         \
            *(f4u*)(obase + 2 * sub + p_) = P[s_][2];                         \
            *(f4u*)(obase + 3 * sub + p_) = P[s_][3];                         \
        } else {                                                              \
            _Pragma("unroll")                                                 \
            for (int o = 0; o < 3; ++o) {                                     \
                obase[p_ + o]           = P[s_][0][o];                        \
                obase[sub + p_ + o]     = P[s_][1][o];                        \
                obase[2 * sub + p_ + o] = P[s_][2][o];                        \
                obase[3 * sub + p_ + o] = P[s_][3][o];                        \
            }                                                                 \
        }                                                                     \
    }                                                                         \
    P[s_][0] = (f4){0.f,0.f,0.f,0.f};  P[s_][1] = (f4){0.f,0.f,0.f,0.f};     \
    P[s_][2] = (f4){0.f,0.f,0.f,0.f};  P[s_][3] = (f4){0.f,0.f,0.f,0.f};     \
} while (0)

// Steady-state rows. Even rows consume b0, prefetch into b1 (taps 0,2,4,6);
// odd rows consume b1, prefetch into b0 (taps 1,3,5,7) and finish one slot.
#define BROW_E(rr_, S0_, S1_, S2_, S3_) do {                                  \
    if ((rr_) + 1 < MIDR) PRE((rr_) + 1, b1a, b1b, b1c, b1d);                 \
    f4 lo, hi; hconv16<MODE>(b0a, b0b, b0c, b0d, lo, hi);                     \
    UPDK(0, S0_); UPDK(2, S1_); UPDK(4, S2_); UPDK(6, S3_);                   \
} while (0)

#define BROW_O(rr_, S0_, S1_, S2_, S3_, FS_, uo_) do {                        \
    if ((rr_) + 1 < MIDR) PRE((rr_) + 1, b0a, b0b, b0c, b0d);                 \
    f4 lo, hi; hconv16<MODE>(b1a, b1b, b1c, b1d, lo, hi);                     \
    UPDK(1, S0_); UPDK(3, S1_); UPDK(5, S2_); UPDK(7, S3_);                   \
    FINS(FS_, uo_);                                                           \
} while (0)

    // ---- prologue: rows 0..5 (static, partial taps; slot = uo & 3) ----
    PRE(0, b0a, b0b, b0c, b0d);
    { PRE(1, b1a,b1b,b1c,b1d); f4 lo, hi; hconv16<MODE>(b0a,b0b,b0c,b0d, lo, hi);
      UPDK(0, 0); }
    { PRE(2, b0a,b0b,b0c,b0d); f4 lo, hi; hconv16<MODE>(b1a,b1b,b1c,b1d, lo, hi);
      UPDK(1, 0); }
    { PRE(3, b1a,b1b,b1c,b1d); f4 lo, hi; hconv16<MODE>(b0a,b0b,b0c,b0d, lo, hi);
      UPDK(0, 1); UPDK(2, 0); }
    { PRE(4, b0a,b0b,b0c,b0d); f4 lo, hi; hconv16<MODE>(b1a,b1b,b1c,b1d, lo, hi);
      UPDK(1, 1); UPDK(3, 0); }
    { PRE(5, b1a,b1b,b1c,b1d); f4 lo, hi; hconv16<MODE>(b0a,b0b,b0c,b0d, lo, hi);
      UPDK(0, 2); UPDK(2, 1); UPDK(4, 0); }
    { PRE(6, b0a,b0b,b0c,b0d); f4 lo, hi; hconv16<MODE>(b1a,b1b,b1c,b1d, lo, hi);
      UPDK(1, 2); UPDK(3, 1); UPDK(5, 0); }

    // ---- steady state: rows 6..29 as 3 x 8-row body (slot schedule is
    //      periodic mod 8; all slot indices compile-time) ----
    #pragma unroll 1
    for (int t = 0; t < 3; ++t) {
        const int r0  = 6 + 8 * t;
        const int uo0 = 4 * t;
        BROW_E(r0,     3, 2, 1, 0);
        BROW_O(r0 + 1, 3, 2, 1, 0, 0, uo0);
        BROW_E(r0 + 2, 0, 3, 2, 1);
        BROW_O(r0 + 3, 0, 3, 2, 1, 1, uo0 + 1);
        BROW_E(r0 + 4, 1, 0, 3, 2);
        BROW_O(r0 + 5, 1, 0, 3, 2, 2, uo0 + 2);
        BROW_E(r0 + 6, 2, 1, 0, 3);
        BROW_O(r0 + 7, 2, 1, 0, 3, 3, uo0 + 3);
    }

#undef BROW_E
#undef BROW_O
#undef FINS
#undef UPDK
#undef PRE
}

__global__ __launch_bounds__(256)
void dwt2_db4_v11(const float* __restrict__ x, float* __restrict__ out) {
    const size_t sub = (size_t)NBC * HO * HO;
    if (blockIdx.x < (unsigned)IBLK) {
        const int id   = blockIdx.x * 256 + threadIdx.x;
        const int cg   = 1 + id % NCGI;            // 1..63: interior
        const int rest = id / NCGI;
        const int st   = rest % NS;
        const int bc   = rest / NS;
        const float* __restrict__ img = x + (size_t)bc * (N * N);
        float* __restrict__ obase = out + (size_t)bc * (HO * HO);
        strip_body<0>(img, obase, sub, 2 * (st * TOH) + 1, st, 4 * cg, 8 * cg - 8);
    } else {
        const int eid  = (blockIdx.x - IBLK) * 256 + threadIdx.x;
        const int side = eid / EHALF;              // wave-uniform (5632 % 64 == 0)
        const int rest = eid % EHALF;
        const int st   = rest % NS;
        const int bc   = rest / NS;
        const float* __restrict__ img = x + (size_t)bc * (N * N);
        float* __restrict__ obase = out + (size_t)bc * (HO * HO);
        const int eh0 = 2 * (st * TOH) + 1;
        if (side == 0) strip_body<-1>(img, obase, sub, eh0, st, 0,   0);
        else           strip_body< 1>(img, obase, sub, eh0, st, 256, N - 16);
    }
}

} // namespace

extern "C" void kernel_launch(void* const* d_in, const int* in_sizes, int n_in,
                              void* d_out, int out_size, void* d_ws, size_t ws_size,
                              hipStream_t stream) {
    const float* x = (const float*)d_in[0];
    float* out = (float*)d_out;
    dwt2_db4_v11<<<IBLK + EBLK, 256, 0, stream>>>(x, out);  // 1430 blocks
}

// Round 12
// 131.199 us; speedup vs baseline: 1.4236x; 1.4236x over previous
//
#include <hip/hip_runtime.h>

// Batched 2D db4 DWT (pywt dwt2, mode='symmetric') over [8,32,512,512] f32.
// Output [4, 8, 32, 259, 259] f32 (LL, LH, HL, HH).
//
//   y[o] = sum_k ext[2o+1+k] * G[k],  G[k] = F[7-k]
//   ext index j -> src:  j<7 -> 6-j ; j<=518 -> j-7 ; else 1030-j
//
// v12: LDS-staged streaming band kernel. Block = (image, 36-row output band),
// 256 threads, walks 78 mid rows in pairs. Staging via global_load_lds
// (dense 1KB/wave-instr, no VGPR round-trip, no per-lane addr VALU) into a
// 3-deep pair-slot LDS ring. Each thread owns 1 output col: hconv from LDS
// (8 floats), vertical accumulation in 16 registers with the v11-verified
// P-slot rotation (period 4 pairs, all indices static). Cols 256-258 ride on
// lanes 0-2 of wave 0 (right-edge reflection). 2048 blocks, 8192 waves.

namespace {

constexpr int N     = 512;
constexpr int HO    = 259;
constexpr int NBC   = 256;
constexpr int TOH   = 36;                  // output rows per band
constexpr int NB    = 8;                   // bands: 8*36 = 288 >= 259
constexpr int NPAIR = (2 * TOH + 6) / 2;   // 39 row-pairs per band
constexpr int LROW  = 520;                 // LDS row stride (floats)

__device__ constexpr float GL[8] = {
     0.23037781330885523f,  0.7148465705525415f,   0.6308807679295904f,
    -0.02798376941698385f, -0.18703481171888114f,  0.030841381835986965f,
     0.032883011666982945f,-0.010597401784997278f};
__device__ constexpr float GH[8] = {
    -0.010597401784997278f,-0.032883011666982945f, 0.030841381835986965f,
     0.18703481171888114f, -0.02798376941698385f, -0.6308807679295904f,
     0.7148465705525415f,  -0.23037781330885523f};

__device__ __forceinline__ int ext_row(int j) {
    int v = j - 7;
    v = (j < 7)     ? (6 - j)         : v;
    v = (j > N + 6) ? (2 * N + 6 - j) : v;
    return v;
}

typedef __attribute__((address_space(1))) const unsigned int ga_u32;
typedef __attribute__((address_space(3))) unsigned int       ls_u32;

__global__ __launch_bounds__(256)
void dwt2_db4_lds(const float* __restrict__ x, float* __restrict__ out) {
    __shared__ float ring[3][2][LROW];

    const int tid  = threadIdx.x;
    const int wv   = tid >> 6;
    const int lane = tid & 63;
    const int band = blockIdx.x & (NB - 1);
    const int bc   = blockIdx.x >> 3;
    const int ho0  = band * TOH;
    const int eh0  = 2 * ho0 + 1;
    const float* __restrict__ img = x + (size_t)bc * (N * N);
    float* __restrict__ ob = out + (size_t)bc * (HO * HO);
    const size_t sub = (size_t)NBC * HO * HO;
    const int c = tid;

    float Pll[4] = {0,0,0,0}, Plh[4] = {0,0,0,0};
    float Phl[4] = {0,0,0,0}, Phh[4] = {0,0,0,0};
    float Qll[4] = {0,0,0,0}, Qlh[4] = {0,0,0,0};
    float Qhl[4] = {0,0,0,0}, Qhh[4] = {0,0,0,0};
    float lo, hi, lo2 = 0.f, hi2 = 0.f;

    int uA = 0, uB = 1, uC = 2;

// wave wv stages half (wv&1) of row 2p+(wv>>1) into pair-slot slot_.
#define STAGE(p_, slot_) do {                                                 \
    const int r_   = 2 * (p_) + (wv >> 1);                                    \
    const int src_ = ext_row(eh0 + r_);                                       \
    const float* g_ = img + (size_t)src_ * N + ((wv & 1) << 8) + (lane << 2); \
    float* l_ = &ring[slot_][wv >> 1][(wv & 1) << 8];                         \
    __builtin_amdgcn_global_load_lds((ga_u32*)g_, (ls_u32*)l_, 16, 0, 0);     \
} while (0)

#define HROW(slot_, half_) do {                                               \
    const float* rp_ = &ring[slot_][half_][0];                                \
    lo = 0.f; hi = 0.f;                                                       \
    if (c >= 3) {                                                             \
        const int b_ = 2 * c - 6;                                             \
        _Pragma("unroll")                                                     \
        for (int f = 0; f < 8; ++f) {                                         \
            const float v_ = rp_[b_ + f];                                     \
            lo = fmaf(v_, GL[f], lo);  hi = fmaf(v_, GH[f], hi);              \
        }                                                                     \
    } else {                                                                  \
        _Pragma("unroll")                                                     \
        for (int f = 0; f < 8; ++f) {                                         \
            const int j_ = 2 * c + 1 + f;                                     \
            const float v_ = rp_[j_ < 7 ? 6 - j_ : j_ - 7];                   \
            lo = fmaf(v_, GL[f], lo);  hi = fmaf(v_, GH[f], hi);              \
        }                                                                     \
    }                                                                         \
    if (tid < 3) {                                                            \
        lo2 = 0.f; hi2 = 0.f;                                                 \
        _Pragma("unroll")                                                     \
        for (int f = 0; f < 8; ++f) {                                         \
            const int j_ = 513 + 2 * tid + f;                                 \
            const float v_ = rp_[j_ <= 518 ? j_ - 7 : 1030 - j_];             \
            lo2 = fmaf(v_, GL[f], lo2);  hi2 = fmaf(v_, GH[f], hi2);          \
        }                                                                     \
    }                                                                         \
} while (0)

#define UPDK(k_, s_) do {                                                     \
    Pll[s_] = fmaf(lo, GL[k_], Pll[s_]);  Plh[s_] = fmaf(lo, GH[k_], Plh[s_]);\
    Phl[s_] = fmaf(hi, GL[k_], Phl[s_]);  Phh[s_] = fmaf(hi, GH[k_], Phh[s_]);\
} while (0)

#define UPDQ(k_, s_) do {                                                     \
    Qll[s_] = fmaf(lo2, GL[k_], Qll[s_]); Qlh[s_] = fmaf(lo2, GH[k_], Qlh[s_]);\
    Qhl[s_] = fmaf(hi2, GL[k_], Qhl[s_]); Qhh[s_] = fmaf(hi2, GH[k_], Qhh[s_]);\
} while (0)

#define FIN(s_, uo_) do {                                                     \
    const int ho_ = ho0 + (uo_);                                              \
    if (ho_ < HO) {                                                           \
        const size_t p_ = (size_t)ho_ * HO + c;                               \
        ob[p_]           = Pll[s_];  ob[sub + p_]     = Plh[s_];              \
        ob[2 * sub + p_] = Phl[s_];  ob[3 * sub + p_] = Phh[s_];              \
        if (tid < 3) {                                                        \
            const size_t q_ = (size_t)ho_ * HO + 256 + tid;                   \
            ob[q_]           = Qll[s_];  ob[sub + q_]     = Qlh[s_];          \
            ob[2 * sub + q_] = Qhl[s_];  ob[3 * sub + q_] = Qhh[s_];          \
        }                                                                     \
    }                                                                         \
    Pll[s_] = 0.f; Plh[s_] = 0.f; Phl[s_] = 0.f; Phh[s_] = 0.f;               \
    Qll[s_] = 0.f; Qlh[s_] = 0.f; Qhl[s_] = 0.f; Qhh[s_] = 0.f;               \
} while (0)

// barrier (all waves done reading pair p's slot), then stage pair p+3 into
// the freed slot, rotate. The stage drains at the NEXT pair's barrier ->
// one full iteration of HBM latency in flight; ready 2 barriers before use.
#define ENDPAIR(p_) do {                                                      \
    __syncthreads();                                                          \
    if ((p_) + 3 < NPAIR) STAGE((p_) + 3, uA);                                \
    const int t_ = uA; uA = uB; uB = uC; uC = t_;                             \
} while (0)

    // ---- prologue: stage pairs 0..2, then pairs 0..2 with partial taps ----
    STAGE(0, 0); STAGE(1, 1); STAGE(2, 2);
    __syncthreads();

    HROW(uA, 0); UPDK(0,0);                       if (tid < 3) { UPDQ(0,0); }
    HROW(uA, 1); UPDK(1,0);                       if (tid < 3) { UPDQ(1,0); }
    ENDPAIR(0);
    HROW(uA, 0); UPDK(0,1); UPDK(2,0);            if (tid < 3) { UPDQ(0,1); UPDQ(2,0); }
    HROW(uA, 1); UPDK(1,1); UPDK(3,0);            if (tid < 3) { UPDQ(1,1); UPDQ(3,0); }
    ENDPAIR(1);
    HROW(uA, 0); UPDK(0,2); UPDK(2,1); UPDK(4,0); if (tid < 3) { UPDQ(0,2); UPDQ(2,1); UPDQ(4,0); }
    HROW(uA, 1); UPDK(1,2); UPDK(3,1); UPDK(5,0); if (tid < 3) { UPDQ(1,2); UPDQ(3,1); UPDQ(5,0); }
    ENDPAIR(2);

    // ---- steady state: pairs 3..38, phase = (p-3)&3, FIN uo = p-3 ----
    #pragma unroll 1
    for (int g = 0; g < 9; ++g) {
        const int p0  = 3 + 4 * g;
        const int uo0 = 4 * g;
        // phase 0
        HROW(uA, 0); UPDK(0,3); UPDK(2,2); UPDK(4,1); UPDK(6,0);
        if (tid < 3) { UPDQ(0,3); UPDQ(2,2); UPDQ(4,1); UPDQ(6,0); }
        HROW(uA, 1); UPDK(1,3); UPDK(3,2); UPDK(5,1); UPDK(7,0);
        if (tid < 3) { UPDQ(1,3); UPDQ(3,2); UPDQ(5,1); UPDQ(7,0); }
        FIN(0, uo0);
        ENDPAIR(p0);
        // phase 1
        HROW(uA, 0); UPDK(0,0); UPDK(2,3); UPDK(4,2); UPDK(6,1);
        if (tid < 3) { UPDQ(0,0); UPDQ(2,3); UPDQ(4,2); UPDQ(6,1); }
        HROW(uA, 1); UPDK(1,0); UPDK(3,3); UPDK(5,2); UPDK(7,1);
        if (tid < 3) { UPDQ(1,0); UPDQ(3,3); UPDQ(5,2); UPDQ(7,1); }
        FIN(1, uo0 + 1);
        ENDPAIR(p0 + 1);
        // phase 2
        HROW(uA, 0); UPDK(0,1); UPDK(2,0); UPDK(4,3); UPDK(6,2);
        if (tid < 3) { UPDQ(0,1); UPDQ(2,0); UPDQ(4,3); UPDQ(6,2); }
        HROW(uA, 1); UPDK(1,1); UPDK(3,0); UPDK(5,3); UPDK(7,2);
        if (tid < 3) { UPDQ(1,1); UPDQ(3,0); UPDQ(5,3); UPDQ(7,2); }
        FIN(2, uo0 + 2);
        ENDPAIR(p0 + 2);
        // phase 3
        HROW(uA, 0); UPDK(0,2); UPDK(2,1); UPDK(4,0); UPDK(6,3);
        if (tid < 3) { UPDQ(0,2); UPDQ(2,1); UPDQ(4,0); UPDQ(6,3); }
        HROW(uA, 1); UPDK(1,2); UPDK(3,1); UPDK(5,0); UPDK(7,3);
        if (tid < 3) { UPDQ(1,2); UPDQ(3,1); UPDQ(5,0); UPDQ(7,3); }
        FIN(3, uo0 + 3);
        ENDPAIR(p0 + 3);
    }

#undef ENDPAIR
#undef FIN
#undef UPDQ
#undef UPDK
#undef HROW
#undef STAGE
}

} // namespace

extern "C" void kernel_launch(void* const* d_in, const int* in_sizes, int n_in,
                              void* d_out, int out_size, void* d_ws, size_t ws_size,
                              hipStream_t stream) {
    const float* x = (const float*)d_in[0];
    float* out = (float*)d_out;
    dwt2_db4_lds<<<NB * NBC, 256, 0, stream>>>(x, out);  // 2048 blocks
}

// Round 13
// 128.251 us; speedup vs baseline: 1.4563x; 1.0230x over previous
//
#include <hip/hip_runtime.h>

// Batched 2D db4 DWT (pywt dwt2, mode='symmetric') over [8,32,512,512] f32.
// Output [4, 8, 32, 259, 259] f32 (LL, LH, HL, HH).
//
//   y[o] = sum_k ext[2o+1+k] * G[k],  G[k] = F[7-k]
//   ext index j -> src:  j<7 -> 6-j ; j<=518 -> j-7 ; else 1030-j
//
// v13 = v12 (global_load_lds staged band walker) with BATCHED barriers:
// 6-deep pair-slot ring, supersteps of {stage 3 pairs, compute 3 pairs,
// sync}. The vmcnt(0) drain the compiler emits before s_barrier now waits
// on stages issued ~3 pair-computes (~900 cy) earlier = HBM latency ->
// exposed stall ~0, and barrier count drops 39 -> 13.
// Slot (p%6) x phase ((p-3)%4) has period 12 pairs = 4 supersteps; steady
// state = 3 x (4-superstep body), all indices literal.

namespace {

constexpr int N     = 512;
constexpr int HO    = 259;
constexpr int NBC   = 256;
constexpr int TOH   = 36;                  // output rows per band
constexpr int NB    = 8;                   // bands: 8*36 = 288 >= 259
constexpr int NPAIR = (2 * TOH + 6) / 2;   // 39 row-pairs per band
constexpr int LROW  = 520;                 // LDS row stride (floats)

__device__ constexpr float GL[8] = {
     0.23037781330885523f,  0.7148465705525415f,   0.6308807679295904f,
    -0.02798376941698385f, -0.18703481171888114f,  0.030841381835986965f,
     0.032883011666982945f,-0.010597401784997278f};
__device__ constexpr float GH[8] = {
    -0.010597401784997278f,-0.032883011666982945f, 0.030841381835986965f,
     0.18703481171888114f, -0.02798376941698385f, -0.6308807679295904f,
     0.7148465705525415f,  -0.23037781330885523f};

__device__ __forceinline__ int ext_row(int j) {
    int v = j - 7;
    v = (j < 7)     ? (6 - j)         : v;
    v = (j > N + 6) ? (2 * N + 6 - j) : v;
    return v;
}

typedef __attribute__((address_space(1))) const unsigned int ga_u32;
typedef __attribute__((address_space(3))) unsigned int       ls_u32;

__global__ __launch_bounds__(256)
void dwt2_db4_v13(const float* __restrict__ x, float* __restrict__ out) {
    __shared__ float ring[6][2][LROW];

    const int tid  = threadIdx.x;
    const int wv   = tid >> 6;
    const int lane = tid & 63;
    const int band = blockIdx.x & (NB - 1);
    const int bc   = blockIdx.x >> 3;
    const int ho0  = band * TOH;
    const int eh0  = 2 * ho0 + 1;
    const float* __restrict__ img = x + (size_t)bc * (N * N);
    float* __restrict__ ob = out + (size_t)bc * (HO * HO);
    const size_t sub = (size_t)NBC * HO * HO;
    const int c = tid;

    float Pll[4] = {0,0,0,0}, Plh[4] = {0,0,0,0};
    float Phl[4] = {0,0,0,0}, Phh[4] = {0,0,0,0};
    float Qll[4] = {0,0,0,0}, Qlh[4] = {0,0,0,0};
    float Qhl[4] = {0,0,0,0}, Qhh[4] = {0,0,0,0};
    float lo, hi, lo2 = 0.f, hi2 = 0.f;

// wave wv stages half (wv&1) of row 2p+(wv>>1) into pair-slot slot_.
#define STAGE(p_, slot_) do {                                                 \
    const int r_   = 2 * (p_) + (wv >> 1);                                    \
    const int src_ = ext_row(eh0 + r_);                                       \
    const float* g_ = img + (size_t)src_ * N + ((wv & 1) << 8) + (lane << 2); \
    float* l_ = &ring[slot_][wv >> 1][(wv & 1) << 8];                         \
    __builtin_amdgcn_global_load_lds((ga_u32*)g_, (ls_u32*)l_, 16, 0, 0);     \
} while (0)

#define STAGE3(p0_, s0_) do {                                                 \
    if ((p0_)     < NPAIR) STAGE((p0_),     (s0_));                           \
    if ((p0_) + 1 < NPAIR) STAGE((p0_) + 1, (s0_) + 1);                       \
    if ((p0_) + 2 < NPAIR) STAGE((p0_) + 2, (s0_) + 2);                       \
} while (0)

#define HROW(slot_, half_) do {                                               \
    const float* rp_ = &ring[slot_][half_][0];                                \
    lo = 0.f; hi = 0.f;                                                       \
    if (c >= 3) {                                                             \
        const int b_ = 2 * c - 6;                                             \
        _Pragma("unroll")                                                     \
        for (int f = 0; f < 8; ++f) {                                         \
            const float v_ = rp_[b_ + f];                                     \
            lo = fmaf(v_, GL[f], lo);  hi = fmaf(v_, GH[f], hi);              \
        }                                                                     \
    } else {                                                                  \
        _Pragma("unroll")                                                     \
        for (int f = 0; f < 8; ++f) {                                         \
            const int j_ = 2 * c + 1 + f;                                     \
            const float v_ = rp_[j_ < 7 ? 6 - j_ : j_ - 7];                   \
            lo = fmaf(v_, GL[f], lo);  hi = fmaf(v_, GH[f], hi);              \
        }                                                                     \
    }                                                                         \
    if (tid < 3) {                                                            \
        lo2 = 0.f; hi2 = 0.f;                                                 \
        _Pragma("unroll")                                                     \
        for (int f = 0; f < 8; ++f) {                                         \
            const int j_ = 513 + 2 * tid + f;                                 \
            const float v_ = rp_[j_ <= 518 ? j_ - 7 : 1030 - j_];             \
            lo2 = fmaf(v_, GL[f], lo2);  hi2 = fmaf(v_, GH[f], hi2);          \
        }                                                                     \
    }                                                                         \
} while (0)

#define UPDK(k_, s_) do {                                                     \
    Pll[s_] = fmaf(lo, GL[k_], Pll[s_]);  Plh[s_] = fmaf(lo, GH[k_], Plh[s_]);\
    Phl[s_] = fmaf(hi, GL[k_], Phl[s_]);  Phh[s_] = fmaf(hi, GH[k_], Phh[s_]);\
} while (0)

#define UPDQ(k_, s_) do {                                                     \
    Qll[s_] = fmaf(lo2, GL[k_], Qll[s_]); Qlh[s_] = fmaf(lo2, GH[k_], Qlh[s_]);\
    Qhl[s_] = fmaf(hi2, GL[k_], Qhl[s_]); Qhh[s_] = fmaf(hi2, GH[k_], Qhh[s_]);\
} while (0)

#define FIN(s_, uo_) do {                                                     \
    const int ho_ = ho0 + (uo_);                                              \
    if (ho_ < HO) {                                                           \
        const size_t p_ = (size_t)ho_ * HO + c;                               \
        ob[p_]           = Pll[s_];  ob[sub + p_]     = Plh[s_];              \
        ob[2 * sub + p_] = Phl[s_];  ob[3 * sub + p_] = Phh[s_];              \
        if (tid < 3) {                                                        \
            const size_t q_ = (size_t)ho_ * HO + 256 + tid;                   \
            ob[q_]           = Qll[s_];  ob[sub + q_]     = Qlh[s_];          \
            ob[2 * sub + q_] = Qhl[s_];  ob[3 * sub + q_] = Qhh[s_];          \
        }                                                                     \
    }                                                                         \
    Pll[s_] = 0.f; Plh[s_] = 0.f; Phl[s_] = 0.f; Phh[s_] = 0.f;               \
    Qll[s_] = 0.f; Qlh[s_] = 0.f; Qhl[s_] = 0.f; Qhh[s_] = 0.f;               \
} while (0)

// Full steady-state pair: slot sl_, phase ph_ (literal 0..3), FIN at uo_.
// Tap->slot: UPDK(2m+e, (3+ph_-m)&3); FIN slot = ph_.
#define PAIRF(sl_, ph_, uo_) do {                                             \
    HROW(sl_, 0);                                                             \
    UPDK(0, (3+(ph_))&3); UPDK(2, (2+(ph_))&3);                               \
    UPDK(4, (1+(ph_))&3); UPDK(6, (ph_)&3);                                   \
    if (tid < 3) { UPDQ(0, (3+(ph_))&3); UPDQ(2, (2+(ph_))&3);                \
                   UPDQ(4, (1+(ph_))&3); UPDQ(6, (ph_)&3); }                  \
    HROW(sl_, 1);                                                             \
    UPDK(1, (3+(ph_))&3); UPDK(3, (2+(ph_))&3);                               \
    UPDK(5, (1+(ph_))&3); UPDK(7, (ph_)&3);                                   \
    if (tid < 3) { UPDQ(1, (3+(ph_))&3); UPDQ(3, (2+(ph_))&3);                \
                   UPDQ(5, (1+(ph_))&3); UPDQ(7, (ph_)&3); }                  \
    FIN((ph_) & 3, uo_);                                                      \
} while (0)

    // ---- prologue ----
    STAGE3(0, 0);                    // pairs 0,1,2 -> slots 0,1,2
    __syncthreads();
    STAGE3(3, 3);                    // pairs 3,4,5 -> slots 3,4,5
    // compute pairs 0,1,2 (partial taps; slot = pair index)
    HROW(0,0); UPDK(0,0);                       if (tid<3) { UPDQ(0,0); }
    HROW(0,1); UPDK(1,0);                       if (tid<3) { UPDQ(1,0); }
    HROW(1,0); UPDK(0,1); UPDK(2,0);            if (tid<3) { UPDQ(0,1); UPDQ(2,0); }
    HROW(1,1); UPDK(1,1); UPDK(3,0);            if (tid<3) { UPDQ(1,1); UPDQ(3,0); }
    HROW(2,0); UPDK(0,2); UPDK(2,1); UPDK(4,0); if (tid<3) { UPDQ(0,2); UPDQ(2,1); UPDQ(4,0); }
    HROW(2,1); UPDK(1,2); UPDK(3,1); UPDK(5,0); if (tid<3) { UPDQ(1,2); UPDQ(3,1); UPDQ(5,0); }
    __syncthreads();

    // ---- steady state: 12 supersteps = 3 x (4-superstep period) ----
    // superstep t: stage pairs 3t+3..3t+5 into freed slots, compute pairs
    // 3t..3t+2 (slots (3t..3t+2)%6, phases ((p-3)%4), FIN uo = p-3), sync.
    #pragma unroll 1
    for (int g = 0; g < 3; ++g) {
        const int pb = 12 * g;          // pair offset of this group
        const int ub = 12 * g;          // uo offset
        // t = 4g+1: compute pairs pb+3..5 (slots 3,4,5; ph 0,1,2)
        STAGE3(pb + 6, 0);
        PAIRF(3, 0, ub + 0); PAIRF(4, 1, ub + 1); PAIRF(5, 2, ub + 2);
        __syncthreads();
        // t = 4g+2: compute pairs pb+6..8 (slots 0,1,2; ph 3,0,1)
        STAGE3(pb + 9, 3);
        PAIRF(0, 3, ub + 3); PAIRF(1, 0, ub + 4); PAIRF(2, 1, ub + 5);
        __syncthreads();
        // t = 4g+3: compute pairs pb+9..11 (slots 3,4,5; ph 2,3,0)
        STAGE3(pb + 12, 0);
        PAIRF(3, 2, ub + 6); PAIRF(4, 3, ub + 7); PAIRF(5, 0, ub + 8);
        __syncthreads();
        // t = 4g+4: compute pairs pb+12..14 (slots 0,1,2; ph 1,2,3)
        STAGE3(pb + 15, 3);
        PAIRF(0, 1, ub + 9); PAIRF(1, 2, ub + 10); PAIRF(2, 3, ub + 11);
        __syncthreads();
    }

#undef PAIRF
#undef FIN
#undef UPDQ
#undef UPDK
#undef HROW
#undef STAGE3
#undef STAGE
}

} // namespace

extern "C" void kernel_launch(void* const* d_in, const int* in_sizes, int n_in,
                              void* d_out, int out_size, void* d_ws, size_t ws_size,
                              hipStream_t stream) {
    const float* x = (const float*)d_in[0];
    float* out = (float*)d_out;
    dwt2_db4_v13<<<NB * NBC, 256, 0, stream>>>(x, out);  // 2048 blocks
}

// Round 14
// 125.268 us; speedup vs baseline: 1.4910x; 1.0238x over previous
//
#include <hip/hip_runtime.h>

// Batched 2D db4 DWT (pywt dwt2, mode='symmetric') over [8,32,512,512] f32.
// Output [4, 8, 32, 259, 259] f32 (LL, LH, HL, HH).
//
//   y[o] = sum_k ext[2o+1+k] * G[k],  G[k] = F[7-k]
//   ext index j -> src:  j<7 -> 6-j ; j<=518 -> j-7 ; else 1030-j
//
// v14 = v13 (global_load_lds 6-slot ring, 3-pair supersteps) rebalanced:
//  - 320-thread blocks: waves 0-3 = branch-free interior cols 3..255
//    (f2-register windows, 4x ds_read_b64/row, stores predicated c>=3);
//    wave 4 = ALL edge cols (lanes 0-2 -> 256-258, lanes 3-5 -> 0-2) via a
//    unified reflect-index scalar path. Removes wave-0's +40 instr/row
//    imbalance that gated block completion.
//  - pair-batched window loads: both rows' 8 f2 loaded before any FMA
//    (8 LDS reads in flight vs serial read->FMA chains).

namespace {

constexpr int N     = 512;
constexpr int HO    = 259;
constexpr int NBC   = 256;
constexpr int TOH   = 36;                  // output rows per band
constexpr int NB    = 8;                   // bands: 8*36 = 288 >= 259
constexpr int NPAIR = 39;                  // row-pairs per band
constexpr int LROW  = 520;                 // LDS row stride (floats)

typedef float f2 __attribute__((ext_vector_type(2)));

__device__ constexpr float GL[8] = {
     0.23037781330885523f,  0.7148465705525415f,   0.6308807679295904f,
    -0.02798376941698385f, -0.18703481171888114f,  0.030841381835986965f,
     0.032883011666982945f,-0.010597401784997278f};
__device__ constexpr float GH[8] = {
    -0.010597401784997278f,-0.032883011666982945f, 0.030841381835986965f,
     0.18703481171888114f, -0.02798376941698385f, -0.6308807679295904f,
     0.7148465705525415f,  -0.23037781330885523f};

__device__ __forceinline__ int ext_row(int j) {
    int v = j - 7;
    v = (j < 7)     ? (6 - j)         : v;
    v = (j > N + 6) ? (2 * N + 6 - j) : v;
    return v;
}

typedef __attribute__((address_space(1))) const unsigned int ga_u32;
typedef __attribute__((address_space(3))) unsigned int       ls_u32;

__global__ __launch_bounds__(320)
void dwt2_db4_v14(const float* __restrict__ x, float* __restrict__ out) {
    __shared__ float ring[6][2][LROW];

    const int tid  = threadIdx.x;
    const int wv   = tid >> 6;
    const int lane = tid & 63;
    const bool w4  = (wv == 4);
    const int band = blockIdx.x & (NB - 1);
    const int bc   = blockIdx.x >> 3;
    const int ho0  = band * TOH;
    const int eh0  = 2 * ho0 + 1;
    const float* __restrict__ img = x + (size_t)bc * (N * N);
    float* __restrict__ ob = out + (size_t)bc * (HO * HO);
    const size_t sub = (size_t)NBC * HO * HO;

    const int  c      = tid;                          // interior col (waves 0-3)
    const int  cb     = (c >= 3) ? (c - 3) : 0;       // f2 window base
    const int  lc     = (lane < 5) ? lane : 5;
    const int  jb     = (lane < 3) ? (513 + 2 * lane) : (2 * lc - 5); // wave-4 tap base
    const int  colOut = w4 ? ((lane < 3) ? (256 + lane) : (lane - 3)) : c;
    const bool valid  = w4 ? (lane < 6) : (c >= 3);

    float Pll[4] = {0,0,0,0}, Plh[4] = {0,0,0,0};
    float Phl[4] = {0,0,0,0}, Phh[4] = {0,0,0,0};
    float lo0, hi0, lo1, hi1;

// wave wv (0-3) stages half (wv&1) of row 2p+(wv>>1) into pair-slot slot_.
#define STAGE(p_, slot_) do {                                                 \
    const int r_   = 2 * (p_) + (wv >> 1);                                    \
    const int src_ = ext_row(eh0 + r_);                                       \
    const float* g_ = img + (size_t)src_ * N + ((wv & 1) << 8) + (lane << 2); \
    float* l_ = &ring[slot_][wv >> 1][(wv & 1) << 8];                         \
    __builtin_amdgcn_global_load_lds((ga_u32*)g_, (ls_u32*)l_, 16, 0, 0);     \
} while (0)

#define STAGE3(p0_, s0_) do {                                                 \
    if ((p0_)     < NPAIR) STAGE((p0_),     (s0_));                           \
    if ((p0_) + 1 < NPAIR) STAGE((p0_) + 1, (s0_) + 1);                       \
    if ((p0_) + 2 < NPAIR) STAGE((p0_) + 2, (s0_) + 2);                       \
} while (0)

// Both rows of pair-slot sl_ -> lo0/hi0 (row0), lo1/hi1 (row1).
#define HPAIR(sl_) do {                                                       \
    if (!w4) {                                                                \
        const f2* r0_ = (const f2*)&ring[sl_][0][0];                          \
        const f2* r1_ = (const f2*)&ring[sl_][1][0];                          \
        const f2 a0_ = r0_[cb], a1_ = r0_[cb+1], a2_ = r0_[cb+2], a3_ = r0_[cb+3]; \
        const f2 b0_ = r1_[cb], b1_ = r1_[cb+1], b2_ = r1_[cb+2], b3_ = r1_[cb+3]; \
        lo0 = a0_.x * GL[0];               hi0 = a0_.x * GH[0];               \
        lo0 = fmaf(a0_.y, GL[1], lo0);     hi0 = fmaf(a0_.y, GH[1], hi0);     \
        lo0 = fmaf(a1_.x, GL[2], lo0);     hi0 = fmaf(a1_.x, GH[2], hi0);     \
        lo0 = fmaf(a1_.y, GL[3], lo0);     hi0 = fmaf(a1_.y, GH[3], hi0);     \
        lo0 = fmaf(a2_.x, GL[4], lo0);     hi0 = fmaf(a2_.x, GH[4], hi0);     \
        lo0 = fmaf(a2_.y, GL[5], lo0);     hi0 = fmaf(a2_.y, GH[5], hi0);     \
        lo0 = fmaf(a3_.x, GL[6], lo0);     hi0 = fmaf(a3_.x, GH[6], hi0);     \
        lo0 = fmaf(a3_.y, GL[7], lo0);     hi0 = fmaf(a3_.y, GH[7], hi0);     \
        lo1 = b0_.x * GL[0];               hi1 = b0_.x * GH[0];               \
        lo1 = fmaf(b0_.y, GL[1], lo1);     hi1 = fmaf(b0_.y, GH[1], hi1);     \
        lo1 = fmaf(b1_.x, GL[2], lo1);     hi1 = fmaf(b1_.x, GH[2], hi1);     \
        lo1 = fmaf(b1_.y, GL[3], lo1);     hi1 = fmaf(b1_.y, GH[3], hi1);     \
        lo1 = fmaf(b2_.x, GL[4], lo1);     hi1 = fmaf(b2_.x, GH[4], hi1);     \
        lo1 = fmaf(b2_.y, GL[5], lo1);     hi1 = fmaf(b2_.y, GH[5], hi1);     \
        lo1 = fmaf(b3_.x, GL[6], lo1);     hi1 = fmaf(b3_.x, GH[6], hi1);     \
        lo1 = fmaf(b3_.y, GL[7], lo1);     hi1 = fmaf(b3_.y, GH[7], hi1);     \
    } else {                                                                  \
        lo0 = 0.f; hi0 = 0.f; lo1 = 0.f; hi1 = 0.f;                           \
        _Pragma("unroll")                                                     \
        for (int f = 0; f < 8; ++f) {                                         \
            const int j_   = jb + f;                                          \
            const int idx_ = (j_ < 7) ? (6 - j_)                              \
                           : ((j_ <= 518) ? (j_ - 7) : (1030 - j_));          \
            const float v0_ = ring[sl_][0][idx_];                             \
            const float v1_ = ring[sl_][1][idx_];                             \
            lo0 = fmaf(v0_, GL[f], lo0);  hi0 = fmaf(v0_, GH[f], hi0);        \
            lo1 = fmaf(v1_, GL[f], lo1);  hi1 = fmaf(v1_, GH[f], hi1);        \
        }                                                                     \
    }                                                                         \
} while (0)

#define UPDK0(k_, s_) do {                                                    \
    Pll[s_] = fmaf(lo0, GL[k_], Pll[s_]); Plh[s_] = fmaf(lo0, GH[k_], Plh[s_]);\
    Phl[s_] = fmaf(hi0, GL[k_], Phl[s_]); Phh[s_] = fmaf(hi0, GH[k_], Phh[s_]);\
} while (0)

#define UPDK1(k_, s_) do {                                                    \
    Pll[s_] = fmaf(lo1, GL[k_], Pll[s_]); Plh[s_] = fmaf(lo1, GH[k_], Plh[s_]);\
    Phl[s_] = fmaf(hi1, GL[k_], Phl[s_]); Phh[s_] = fmaf(hi1, GH[k_], Phh[s_]);\
} while (0)

#define FIN(s_, uo_) do {                                                     \
    const int ho_ = ho0 + (uo_);                                              \
    if (valid && ho_ < HO) {                                                  \
        const size_t p_ = (size_t)ho_ * HO + colOut;                          \
        ob[p_]           = Pll[s_];  ob[sub + p_]     = Plh[s_];              \
        ob[2 * sub + p_] = Phl[s_];  ob[3 * sub + p_] = Phh[s_];              \
    }                                                                         \
    Pll[s_] = 0.f; Plh[s_] = 0.f; Phl[s_] = 0.f; Phh[s_] = 0.f;               \
} while (0)

// Full steady-state pair: slot sl_, phase ph_ (literal 0..3), FIN at uo_.
#define PAIRF(sl_, ph_, uo_) do {                                             \
    HPAIR(sl_);                                                               \
    UPDK0(0, (3+(ph_))&3); UPDK0(2, (2+(ph_))&3);                             \
    UPDK0(4, (1+(ph_))&3); UPDK0(6, (ph_)&3);                                 \
    UPDK1(1, (3+(ph_))&3); UPDK1(3, (2+(ph_))&3);                             \
    UPDK1(5, (1+(ph_))&3); UPDK1(7, (ph_)&3);                                 \
    FIN((ph_) & 3, uo_);                                                      \
} while (0)

    // ---- prologue ----
    if (!w4) STAGE3(0, 0);           // pairs 0,1,2 -> slots 0,1,2
    __syncthreads();
    if (!w4) STAGE3(3, 3);           // pairs 3,4,5 -> slots 3,4,5
    // compute pairs 0,1,2 (partial taps; slot = pair index)
    HPAIR(0); UPDK0(0,0);                       UPDK1(1,0);
    HPAIR(1); UPDK0(0,1); UPDK0(2,0);           UPDK1(1,1); UPDK1(3,0);
    HPAIR(2); UPDK0(0,2); UPDK0(2,1); UPDK0(4,0);
              UPDK1(1,2); UPDK1(3,1); UPDK1(5,0);
    __syncthreads();

    // ---- steady state: 12 supersteps = 3 x (4-superstep period) ----
    #pragma unroll 1
    for (int g = 0; g < 3; ++g) {
        const int pb = 12 * g;
        const int ub = 12 * g;
        STAGE_GROUP_1:;
        if (!w4) STAGE3(pb + 6, 0);
        PAIRF(3, 0, ub + 0); PAIRF(4, 1, ub + 1); PAIRF(5, 2, ub + 2);
        __syncthreads();
        if (!w4) STAGE3(pb + 9, 3);
        PAIRF(0, 3, ub + 3); PAIRF(1, 0, ub + 4); PAIRF(2, 1, ub + 5);
        __syncthreads();
        if (!w4) STAGE3(pb + 12, 0);
        PAIRF(3, 2, ub + 6); PAIRF(4, 3, ub + 7); PAIRF(5, 0, ub + 8);
        __syncthreads();
        if (!w4) STAGE3(pb + 15, 3);
        PAIRF(0, 1, ub + 9); PAIRF(1, 2, ub + 10); PAIRF(2, 3, ub + 11);
        __syncthreads();
    }

#undef PAIRF
#undef FIN
#undef UPDK1
#undef UPDK0
#undef HPAIR
#undef STAGE3
#undef STAGE
}

} // namespace

extern "C" void kernel_launch(void* const* d_in, const int* in_sizes, int n_in,
                              void* d_out, int out_size, void* d_ws, size_t ws_size,
                              hipStream_t stream) {
    const float* x = (const float*)d_in[0];
    float* out = (float*)d_out;
    dwt2_db4_v14<<<NB * NBC, 320, 0, stream>>>(x, out);  // 2048 blocks
}

// Round 19
// 125.237 us; speedup vs baseline: 1.4914x; 1.0002x over previous
//
#include <hip/hip_runtime.h>

// Batched 2D db4 DWT (pywt dwt2, mode='symmetric') over [8,32,512,512] f32.
// Output [4, 8, 32, 259, 259] f32 (LL, LH, HL, HH).
//
//   y[o] = sum_k ext[2o+1+k] * G[k],  G[k] = F[7-k]
//   ext index j -> src:  j<7 -> 6-j ; j<=518 -> j-7 ; else 1030-j
//
// v19 = v14 restored verbatim (verified best: 125.3 us, absmax 0).
// The v15-v18 barrier-free branch (per-wave counted-vmcnt pipeline) is
// abandoned: gload_lds -> same-wave ds_read with counted vmcnt and NO
// s_barrier produced persistent stale-LDS errors despite schedule- and
// count-verified waits; every HW-verified pattern interposes a barrier.
//
// Structure: global_load_lds 6-slot pair ring, supersteps {stage 3 pairs,
// compute 3 pairs, __syncthreads}; 320-thread blocks: waves 0-3 branch-free
// interior cols (f2 register windows), wave 4 all 6 edge cols.

namespace {

constexpr int N     = 512;
constexpr int HO    = 259;
constexpr int NBC   = 256;
constexpr int TOH   = 36;                  // output rows per band
constexpr int NB    = 8;                   // bands: 8*36 = 288 >= 259
constexpr int NPAIR = 39;                  // row-pairs per band
constexpr int LROW  = 520;                 // LDS row stride (floats)

typedef float f2 __attribute__((ext_vector_type(2)));

__device__ constexpr float GL[8] = {
     0.23037781330885523f,  0.7148465705525415f,   0.6308807679295904f,
    -0.02798376941698385f, -0.18703481171888114f,  0.030841381835986965f,
     0.032883011666982945f,-0.010597401784997278f};
__device__ constexpr float GH[8] = {
    -0.010597401784997278f,-0.032883011666982945f, 0.030841381835986965f,
     0.18703481171888114f, -0.02798376941698385f, -0.6308807679295904f,
     0.7148465705525415f,  -0.23037781330885523f};

__device__ __forceinline__ int ext_row(int j) {
    int v = j - 7;
    v = (j < 7)     ? (6 - j)         : v;
    v = (j > N + 6) ? (2 * N + 6 - j) : v;
    return v;
}

typedef __attribute__((address_space(1))) const unsigned int ga_u32;
typedef __attribute__((address_space(3))) unsigned int       ls_u32;

__global__ __launch_bounds__(320)
void dwt2_db4_v19(const float* __restrict__ x, float* __restrict__ out) {
    __shared__ float ring[6][2][LROW];

    const int tid  = threadIdx.x;
    const int wv   = tid >> 6;
    const int lane = tid & 63;
    const bool w4  = (wv == 4);
    const int band = blockIdx.x & (NB - 1);
    const int bc   = blockIdx.x >> 3;
    const int ho0  = band * TOH;
    const int eh0  = 2 * ho0 + 1;
    const float* __restrict__ img = x + (size_t)bc * (N * N);
    float* __restrict__ ob = out + (size_t)bc * (HO * HO);
    const size_t sub = (size_t)NBC * HO * HO;

    const int  c      = tid;                          // interior col (waves 0-3)
    const int  cb     = (c >= 3) ? (c - 3) : 0;       // f2 window base
    const int  lc     = (lane < 5) ? lane : 5;
    const int  jb     = (lane < 3) ? (513 + 2 * lane) : (2 * lc - 5); // wave-4 tap base
    const int  colOut = w4 ? ((lane < 3) ? (256 + lane) : (lane - 3)) : c;
    const bool valid  = w4 ? (lane < 6) : (c >= 3);

    float Pll[4] = {0,0,0,0}, Plh[4] = {0,0,0,0};
    float Phl[4] = {0,0,0,0}, Phh[4] = {0,0,0,0};
    float lo0, hi0, lo1, hi1;

// wave wv (0-3) stages half (wv&1) of row 2p+(wv>>1) into pair-slot slot_.
#define STAGE(p_, slot_) do {                                                 \
    const int r_   = 2 * (p_) + (wv >> 1);                                    \
    const int src_ = ext_row(eh0 + r_);                                       \
    const float* g_ = img + (size_t)src_ * N + ((wv & 1) << 8) + (lane << 2); \
    float* l_ = &ring[slot_][wv >> 1][(wv & 1) << 8];                         \
    __builtin_amdgcn_global_load_lds((ga_u32*)g_, (ls_u32*)l_, 16, 0, 0);     \
} while (0)

#define STAGE3(p0_, s0_) do {                                                 \
    if ((p0_)     < NPAIR) STAGE((p0_),     (s0_));                           \
    if ((p0_) + 1 < NPAIR) STAGE((p0_) + 1, (s0_) + 1);                       \
    if ((p0_) + 2 < NPAIR) STAGE((p0_) + 2, (s0_) + 2);                       \
} while (0)

// Both rows of pair-slot sl_ -> lo0/hi0 (row0), lo1/hi1 (row1).
#define HPAIR(sl_) do {                                                       \
    if (!w4) {                                                                \
        const f2* r0_ = (const f2*)&ring[sl_][0][0];                          \
        const f2* r1_ = (const f2*)&ring[sl_][1][0];                          \
        const f2 a0_ = r0_[cb], a1_ = r0_[cb+1], a2_ = r0_[cb+2], a3_ = r0_[cb+3]; \
        const f2 b0_ = r1_[cb], b1_ = r1_[cb+1], b2_ = r1_[cb+2], b3_ = r1_[cb+3]; \
        lo0 = a0_.x * GL[0];               hi0 = a0_.x * GH[0];               \
        lo0 = fmaf(a0_.y, GL[1], lo0);     hi0 = fmaf(a0_.y, GH[1], hi0);     \
        lo0 = fmaf(a1_.x, GL[2], lo0);     hi0 = fmaf(a1_.x, GH[2], hi0);     \
        lo0 = fmaf(a1_.y, GL[3], lo0);     hi0 = fmaf(a1_.y, GH[3], hi0);     \
        lo0 = fmaf(a2_.x, GL[4], lo0);     hi0 = fmaf(a2_.x, GH[4], hi0);     \
        lo0 = fmaf(a2_.y, GL[5], lo0);     hi0 = fmaf(a2_.y, GH[5], hi0);     \
        lo0 = fmaf(a3_.x, GL[6], lo0);     hi0 = fmaf(a3_.x, GH[6], hi0);     \
        lo0 = fmaf(a3_.y, GL[7], lo0);     hi0 = fmaf(a3_.y, GH[7], hi0);     \
        lo1 = b0_.x * GL[0];               hi1 = b0_.x * GH[0];               \
        lo1 = fmaf(b0_.y, GL[1], lo1);     hi1 = fmaf(b0_.y, GH[1], hi1);     \
        lo1 = fmaf(b1_.x, GL[2], lo1);     hi1 = fmaf(b1_.x, GH[2], hi1);     \
        lo1 = fmaf(b1_.y, GL[3], lo1);     hi1 = fmaf(b1_.y, GH[3], hi1);     \
        lo1 = fmaf(b2_.x, GL[4], lo1);     hi1 = fmaf(b2_.x, GH[4], hi1);     \
        lo1 = fmaf(b2_.y, GL[5], lo1);     hi1 = fmaf(b2_.y, GH[5], hi1);     \
        lo1 = fmaf(b3_.x, GL[6], lo1);     hi1 = fmaf(b3_.x, GH[6], hi1);     \
        lo1 = fmaf(b3_.y, GL[7], lo1);     hi1 = fmaf(b3_.y, GH[7], hi1);     \
    } else {                                                                  \
        lo0 = 0.f; hi0 = 0.f; lo1 = 0.f; hi1 = 0.f;                           \
        _Pragma("unroll")                                                     \
        for (int f = 0; f < 8; ++f) {                                         \
            const int j_   = jb + f;                                          \
            const int idx_ = (j_ < 7) ? (6 - j_)                              \
                           : ((j_ <= 518) ? (j_ - 7) : (1030 - j_));          \
            const float v0_ = ring[sl_][0][idx_];                             \
            const float v1_ = ring[sl_][1][idx_];                             \
            lo0 = fmaf(v0_, GL[f], lo0);  hi0 = fmaf(v0_, GH[f], hi0);        \
            lo1 = fmaf(v1_, GL[f], lo1);  hi1 = fmaf(v1_, GH[f], hi1);        \
        }                                                                     \
    }                                                                         \
} while (0)

#define UPDK0(k_, s_) do {                                                    \
    Pll[s_] = fmaf(lo0, GL[k_], Pll[s_]); Plh[s_] = fmaf(lo0, GH[k_], Plh[s_]);\
    Phl[s_] = fmaf(hi0, GL[k_], Phl[s_]); Phh[s_] = fmaf(hi0, GH[k_], Phh[s_]);\
} while (0)

#define UPDK1(k_, s_) do {                                                    \
    Pll[s_] = fmaf(lo1, GL[k_], Pll[s_]); Plh[s_] = fmaf(lo1, GH[k_], Plh[s_]);\
    Phl[s_] = fmaf(hi1, GL[k_], Phl[s_]); Phh[s_] = fmaf(hi1, GH[k_], Phh[s_]);\
} while (0)

#define FIN(s_, uo_) do {                                                     \
    const int ho_ = ho0 + (uo_);                                              \
    if (valid && ho_ < HO) {                                                  \
        const size_t p_ = (size_t)ho_ * HO + colOut;                          \
        ob[p_]           = Pll[s_];  ob[sub + p_]     = Plh[s_];              \
        ob[2 * sub + p_] = Phl[s_];  ob[3 * sub + p_] = Phh[s_];              \
    }                                                                         \
    Pll[s_] = 0.f; Plh[s_] = 0.f; Phl[s_] = 0.f; Phh[s_] = 0.f;               \
} while (0)

// Full steady-state pair: slot sl_, phase ph_ (literal 0..3), FIN at uo_.
#define PAIRF(sl_, ph_, uo_) do {                                             \
    HPAIR(sl_);                                                               \
    UPDK0(0, (3+(ph_))&3); UPDK0(2, (2+(ph_))&3);                             \
    UPDK0(4, (1+(ph_))&3); UPDK0(6, (ph_)&3);                                 \
    UPDK1(1, (3+(ph_))&3); UPDK1(3, (2+(ph_))&3);                             \
    UPDK1(5, (1+(ph_))&3); UPDK1(7, (ph_)&3);                                 \
    FIN((ph_) & 3, uo_);                                                      \
} while (0)

    // ---- prologue ----
    if (!w4) STAGE3(0, 0);           // pairs 0,1,2 -> slots 0,1,2
    __syncthreads();
    if (!w4) STAGE3(3, 3);           // pairs 3,4,5 -> slots 3,4,5
    // compute pairs 0,1,2 (partial taps; slot = pair index)
    HPAIR(0); UPDK0(0,0);                       UPDK1(1,0);
    HPAIR(1); UPDK0(0,1); UPDK0(2,0);           UPDK1(1,1); UPDK1(3,0);
    HPAIR(2); UPDK0(0,2); UPDK0(2,1); UPDK0(4,0);
              UPDK1(1,2); UPDK1(3,1); UPDK1(5,0);
    __syncthreads();

    // ---- steady state: 12 supersteps = 3 x (4-superstep period) ----
    #pragma unroll 1
    for (int g = 0; g < 3; ++g) {
        const int pb = 12 * g;
        const int ub = 12 * g;
        if (!w4) STAGE3(pb + 6, 0);
        PAIRF(3, 0, ub + 0); PAIRF(4, 1, ub + 1); PAIRF(5, 2, ub + 2);
        __syncthreads();
        if (!w4) STAGE3(pb + 9, 3);
        PAIRF(0, 3, ub + 3); PAIRF(1, 0, ub + 4); PAIRF(2, 1, ub + 5);
        __syncthreads();
        if (!w4) STAGE3(pb + 12, 0);
        PAIRF(3, 2, ub + 6); PAIRF(4, 3, ub + 7); PAIRF(5, 0, ub + 8);
        __syncthreads();
        if (!w4) STAGE3(pb + 15, 3);
        PAIRF(0, 1, ub + 9); PAIRF(1, 2, ub + 10); PAIRF(2, 3, ub + 11);
        __syncthreads();
    }

#undef PAIRF
#undef FIN
#undef UPDK1
#undef UPDK0
#undef HPAIR
#undef STAGE3
#undef STAGE
}

} // namespace

extern "C" void kernel_launch(void* const* d_in, const int* in_sizes, int n_in,
                              void* d_out, int out_size, void* d_ws, size_t ws_size,
                              hipStream_t stream) {
    const float* x = (const float*)d_in[0];
    float* out = (float*)d_out;
    dwt2_db4_v19<<<NB * NBC, 320, 0, stream>>>(x, out);  // 2048 blocks
}